// Round 4
// baseline (198.887 us; speedup 1.0000x reference)
//
#include <hip/hip_runtime.h>
#include <cstdint>
#include <cstddef>

// KAN layer: out[b,j] = sum_{i,k} basis_k(tanh x[b,i]) * C[j,i,k]
// basis is 2-sparse (adjacent slots lo, lo+1); pad to 16 slots/i.
// R15: R14's 4-phase schedule with the x-pipeline OFF-BY-ONE fixed.
// R14 overwrote xn (x holding it+1) with x(it+2) in phase 0 before the
// expand in phases 1-2 consumed it, and expanded stale xc=x(0) in iter 0
// (absmax 2.74). R15 restores R13's proven 2-deep pipeline: xc holds
// x(it+1) at iter start (expanded this iter into As[nxt]); xn = x(it+2)
// loaded in phase 0; xc = xn at iter end.
// Schedule per 4-i iter (256x256 block, 8 waves, 128 KB LDS, 1 block/CU):
// 4 phases (ks x m-half), each {ds_read frags || stage-chunk || expand-half
// -> s_barrier -> lgkmcnt(0)+sched_barrier -> setprio(1) 16 MFMA setprio(0)
// -> s_barrier}. Intra-iter barriers are schedule shaping only (reads hit
// cur buffers, writes hit nxt); the iter-end __syncthreads is the real
// handoff (drains vmcnt for global_load_lds + makes ds_writes visible).

typedef _Float16 half2_v __attribute__((ext_vector_type(2)));
typedef __fp16  fp16x2  __attribute__((ext_vector_type(2)));
typedef _Float16 f16x8 __attribute__((ext_vector_type(8)));
typedef float f32x4 __attribute__((ext_vector_type(4)));

__device__ __forceinline__ half2_v u32_as_h2(uint32_t u) {
  union { uint32_t u; half2_v h; } c; c.u = u; return c.h;
}
__device__ __forceinline__ uint32_t h2_as_u32(half2_v h) {
  union { uint32_t u; half2_v h; } c; c.h = h; return c.u;
}
__device__ __forceinline__ half2_v cvt_pk_h2(float a, float b) {
  union { fp16x2 f; half2_v h; } c;
  c.f = __builtin_amdgcn_cvt_pkrtz(a, b);
  return c.h;
}
__device__ __forceinline__ float dot2f(half2_v a, half2_v b, float c) {
#if __has_builtin(__builtin_amdgcn_fdot2)
  return __builtin_amdgcn_fdot2(a, b, c, false);
#else
  return c + (float)a[0] * (float)b[0] + (float)a[1] * (float)b[1];
#endif
}
__device__ __forceinline__ uint16_t f16_bits(float v) {
  union { _Float16 h; uint16_t u; } c; c.h = (_Float16)v; return c.u;
}

__device__ __forceinline__ float fast_tanhf(float v) {
  const float e = __expf(2.0f * v);
  return 1.0f - 2.0f / (e + 1.0f);
}

// ---- basis-weight computation (analytic uniform knots; verified R10) ----
#define KSTEP 0.13333333333333333f
#define KINV  7.49999943750004f      // 1/(2/15 + 1e-8)
__device__ __forceinline__ void kan_weights(float xin, float& w0, float& w1, int& lo) {
  float xc = fast_tanhf(xin);
  xc = fminf(fmaxf(xc, -1.0f), 1.0f);
  int m = (int)((xc + 1.0f) * 7.5f);   // interval index; basis continuity makes +-1 ULP safe
  m = min(max(m, 0), 14);
  const float k0 = fmaf((float)m, KSTEP, -1.0f);
  const float up = (xc - k0) * KINV;
  const float dn = (k0 + KSTEP - xc) * KINV;
  // m==0: up on slot 0 | 1<=m<=11: dn on m-1, up on m | m==12: dn on 11 | m>=13: zero
  w0 = (m == 0) ? up : ((m <= 12) ? dn : 0.0f);
  w1 = (m >= 1 && m <= 11) ? up : 0.0f;
  lo = min(max(m - 1, 0), 11);
}

__device__ __forceinline__ void load_lds16(const void* g, void* l) {
  __builtin_amdgcn_global_load_lds((const __attribute__((address_space(1))) void*)g,
                                   (__attribute__((address_space(3))) void*)l, 16, 0, 0);
}

// ================= fast path =================
#define GMM 8192
#define GNN 256
#define KI  16                 // padded slots per i
#define GK2 (1024 * KI)        // 16384
#define KSPL2 8
#define IPER (1024 / KSPL2)    // 128 i per split
#define BM2 256
#define BN2 256
#define NIT (IPER / 4)         // 32 pipeline iters (4 i each)

// prep_B2: f16 B2[j][i*16+s], s=0..11 from coef, 12..15 zero (slot12 unused).
// Also zeroes out[] (replaces the separate memset dispatch).
__global__ __launch_bounds__(256)
void kan_prep_B2(const float* __restrict__ coef, uint32_t* __restrict__ B2,
                 float4* __restrict__ outz) {
  const int tid = blockIdx.x * 256 + threadIdx.x;   // flat (j,i), 262144
  const float* cp = coef + (size_t)tid * 13;
  uint32_t w[8];
#pragma unroll
  for (int q = 0; q < 6; ++q) w[q] = h2_as_u32(cvt_pk_h2(cp[2 * q], cp[2 * q + 1]));
  w[6] = 0u; w[7] = 0u;
  uint4* p = (uint4*)(B2 + (size_t)tid * 8);
  p[0] = make_uint4(w[0], w[1], w[2], w[3]);
  p[1] = make_uint4(w[4], w[5], w[6], w[7]);
  // out: 8192*256 f32 = 524288 float4; 262144 threads x 2
  const float4 z = make_float4(0.f, 0.f, 0.f, 0.f);
  outz[tid] = z;
  outz[tid + 262144] = z;
}

__global__ __launch_bounds__(512, 2)
void kan_gemm9(const float* __restrict__ x, const _Float16* __restrict__ B2,
               float* __restrict__ out) {
  // Bs: double-buffered 2x32 KB (XOR-swizzled on the global side since
  // global_load_lds LDS addr = uniform base + lane*16).
  // As: double-buffered 2x32 KB expanded A-panel [4 i][256 rows][16 f16],
  // with 16-B halves swapped when (row>>2)&1 (bank spread).
  __shared__ __align__(16) char Bs[2][BN2 * 128];
  __shared__ __align__(16) char As[2][4 * BM2 * 32];

  const int t    = threadIdx.x;
  const int lane = t & 63;
  const int wv   = t >> 6;          // 0..7
  const int mw   = wv & 1;          // m-half of block (128)
  const int nw   = wv >> 1;         // n-quarter of block (64)
  const int fr   = lane & 15;
  const int fq   = lane >> 4;
  const int m0   = blockIdx.z * BM2;
  const int i00  = blockIdx.x * IPER;
  const int fr_swz = ((fr >> 2) & 1) * 16;   // A-panel half-swap bit for reads
  const int a_half = (fq & 1) * 16;          // logical 16-B half within 16-slot row

  f32x4 acc[8][4];
#pragma unroll
  for (int a = 0; a < 8; ++a)
#pragma unroll
    for (int b = 0; b < 4; ++b) acc[a][b] = (f32x4){0.f, 0.f, 0.f, 0.f};

  // B staging: 2048 16-B chunks (4/thread), XOR swizzle applied on global side.
  const int sn[4] = { (0 * 512 + t) >> 3, (1 * 512 + t) >> 3,
                      (2 * 512 + t) >> 3, (3 * 512 + t) >> 3 };
  const int sc = t & 7;
  // A-panel production: thread t -> row p_row, i-pair {p_ip, p_ip+1}.
  const int p_row = t & 255;
  const int p_ip  = (t >> 8) * 2;   // 0 or 2
  const int p_swz = ((p_row >> 2) & 1) * 16;
  const float* xrow = x + (size_t)(m0 + p_row) * 1024 + p_ip;

  auto stage1 = [&](const _Float16* Bb, char* Bnx, int s) {
    const int c = sc ^ (sn[s] & 7);
    load_lds16(Bb + (size_t)sn[s] * GK2 + c * 8, Bnx + (s * 512 + t) * 16);
  };
  auto loadx = [&](int it) -> float2 {
    return *(const float2*)(xrow + i00 + it * 4);
  };
  // expand one i-row: zero the 32-B row (halves in swizzled order so each
  // instruction's 64 lanes cover all 8 bank groups), then scatter (w0,w1).
  auto expand_half = [&](char* Anx, float xv, int d) {
    float w0, w1; int lo;
    kan_weights(xv, w0, w1, lo);
    const uint32_t wp  = (uint32_t)f16_bits(w0) | ((uint32_t)f16_bits(w1) << 16);
    const uint32_t wlo = (lo & 1) ? (wp << 16) : wp;
    const uint32_t whi = (lo & 1) ? (wp >> 16) : 0u;
    const int w = lo >> 1;                      // u32 word 0..5
    char* rb = Anx + (size_t)((p_ip + d) * BM2 + p_row) * 32;
    *(uint4*)(rb + p_swz)        = make_uint4(0u, 0u, 0u, 0u);
    *(uint4*)(rb + (p_swz ^ 16)) = make_uint4(0u, 0u, 0u, 0u);
    *(uint32_t*)(rb + (((w + 1) * 4) ^ p_swz)) = whi;  // distinct word from wlo
    *(uint32_t*)(rb + ((w * 4) ^ p_swz))       = wlo;
  };

// phase MFMA cluster: barrier -> lgkm drain (pin with sched_barrier, rule #18)
// -> setprio(1) 16 MFMA setprio(0). Closing barrier placed by caller.
#define MFMA_CLUSTER(MH)                                                        \
  __builtin_amdgcn_s_barrier();                                                 \
  asm volatile("s_waitcnt lgkmcnt(0)" ::: "memory");                            \
  __builtin_amdgcn_sched_barrier(0);                                            \
  __builtin_amdgcn_s_setprio(1);                                                \
  _Pragma("unroll")                                                             \
  for (int q = 0; q < 4; ++q)                                                   \
    _Pragma("unroll")                                                           \
    for (int ni = 0; ni < 4; ++ni)                                              \
      acc[(MH) * 4 + q][ni] = __builtin_amdgcn_mfma_f32_16x16x32_f16(           \
          af[q], bf[ni], acc[(MH) * 4 + q][ni], 0, 0, 0);                       \
  __builtin_amdgcn_s_setprio(0);

  // ---- prologue ----
  // x(0) loaded & expanded into As[0] now; then xc <- x(1) so the loop
  // invariant holds: at iter start, xc = x(it+1) (expanded this iter).
  float2 xc = loadx(0);
  {
    const _Float16* Bb0 = B2 + (size_t)i00 * KI;
    char* B0 = (char*)Bs[0];
#pragma unroll
    for (int s = 0; s < 4; ++s) stage1(Bb0, B0, s);
  }
  expand_half((char*)As[0], xc.x, 0);
  expand_half((char*)As[0], xc.y, 1);
  xc = loadx(1);
  __syncthreads();

  for (int it = 0; it < NIT; ++it) {
    const int cur = it & 1;
    const char* Bd = (const char*)Bs[cur];
    const char* Ad = (const char*)As[cur];
    char* Bnx = (char*)Bs[cur ^ 1];
    char* Anx = (char*)As[cur ^ 1];
    const bool pre = (it + 1 < NIT);
    const _Float16* Bb = B2 + (size_t)(i00 + (it + 1) * 4) * KI;

    f16x8 af[4], bf[4];
    float2 xn;

    auto rd_b = [&](int ks) {
#pragma unroll
      for (int ni = 0; ni < 4; ++ni) {
        const int row = nw * 64 + ni * 16 + fr;
        bf[ni] = *(const f16x8*)(Bd + (row * 8 + ((ks * 4 + fq) ^ (row & 7))) * 16);
      }
    };
    auto rd_a = [&](int ks, int mh) {
      const int iloc = ks * 2 + (fq >> 1);
#pragma unroll
      for (int q = 0; q < 4; ++q)
        af[q] = *(const f16x8*)(Ad +
            (size_t)((iloc * BM2 + mw * 128 + mh * 64 + q * 16 + fr) * 32) +
            (a_half ^ fr_swz));
    };

    // ---- phase 0: (ks0, mh0); issue 2 stage chunks + x(it+2) load early ----
    rd_b(0); rd_a(0, 0);
    if (pre) { stage1(Bb, Bnx, 0); stage1(Bb, Bnx, 1); }
    xn = loadx((it + 2 < NIT) ? it + 2 : NIT - 1);   // dummy at tail, value unused
    MFMA_CLUSTER(0)
    __builtin_amdgcn_s_barrier();

    // ---- phase 1: (ks0, mh1); expand x(it+1) half 0 into As[nxt] ----
    rd_a(0, 1);
    if (pre) { stage1(Bb, Bnx, 2); expand_half(Anx, xc.x, 0); }
    MFMA_CLUSTER(1)
    __builtin_amdgcn_s_barrier();

    // ---- phase 2: (ks1, mh0); expand x(it+1) half 1 ----
    rd_b(1); rd_a(1, 0);
    if (pre) { stage1(Bb, Bnx, 3); expand_half(Anx, xc.y, 1); }
    MFMA_CLUSTER(0)
    __builtin_amdgcn_s_barrier();

    // ---- phase 3: (ks1, mh1); nothing staged here so the iter-end drain
    //      only waits on ops issued >=1 phase ago ----
    rd_a(1, 1);
    MFMA_CLUSTER(1)
    xc = xn;           // commit pipeline: xc = x(it+2) for next iter's expand
    __syncthreads();   // iter handoff: As/Bs[nxt] writes visible, asyncs drained
  }
#undef MFMA_CLUSTER

#pragma unroll
  for (int mi = 0; mi < 8; ++mi) {
    const int gr = m0 + mw * 128 + mi * 16 + fq * 4;
#pragma unroll
    for (int ni = 0; ni < 4; ++ni) {
      const int gc = nw * 64 + ni * 16 + fr;
#pragma unroll
      for (int r = 0; r < 4; ++r)
        atomicAdd(&out[(size_t)(gr + r) * GNN + gc], acc[mi][ni][r]);
    }
  }
}

// ================= fallback: direct dot2 path (no workspace) =================
#define TI 8
#define BT 256
#define JT 32
#define ISPL 2
#define IRANGE (1024 / ISPL)

__global__ __launch_bounds__(256)
void kan_dot2(const float* __restrict__ x, const float* __restrict__ coef,
              float* __restrict__ out) {
  __shared__ uint32_t Plds[TI * 12 * JT];
  const int t    = threadIdx.x;
  const int b    = blockIdx.x * BT + t;
  const int j0   = blockIdx.y * JT;
  const int cbeg = blockIdx.z * (IRANGE / TI);

  float acc[JT];
#pragma unroll
  for (int q = 0; q < JT; ++q) acc[q] = 0.0f;

  const int s_jj   = t & 31;
  const int s_iloc = t >> 5;

  for (int c = cbeg; c < cbeg + IRANGE / TI; ++c) {
    const int i0 = c * TI;
    __syncthreads();
    {
      const float* cp0 = coef + ((size_t)(j0 + s_jj) * 1024 + (i0 + s_iloc)) * 13;
      float cv[13];
#pragma unroll
      for (int s = 0; s < 13; ++s) cv[s] = cp0[s];
#pragma unroll
      for (int r = 0; r < 12; ++r) {
        half2_v h; h[0] = (_Float16)cv[r]; h[1] = (_Float16)cv[r + 1];
        const int slot = ((s_jj >> 2) + r) & 7;
        Plds[(s_iloc * 12 + r) * 32 + slot * 4 + (s_jj & 3)] = h2_as_u32(h);
      }
    }
    uint32_t wr[TI]; int lor[TI];
    {
      const float* xr = x + (size_t)b * 1024 + i0;
      const float4 xa = *(const float4*)(xr);
      const float4 xb = *(const float4*)(xr + 4);
      const float xv[TI] = {xa.x, xa.y, xa.z, xa.w, xb.x, xb.y, xb.z, xb.w};
#pragma unroll
      for (int q = 0; q < TI; ++q) {
        float w0, w1; int lo;
        kan_weights(xv[q], w0, w1, lo);
        wr[q] = (uint32_t)f16_bits(w0) | ((uint32_t)f16_bits(w1) << 16);
        lor[q] = lo;
      }
    }
    __syncthreads();

    const uint4* P4 = (const uint4*)Plds;
#pragma unroll
    for (int ii = 0; ii < TI; ++ii) {
      const half2_v hw = u32_as_h2(wr[ii]);
      const int lo = lor[ii];
      const int base = (ii * 12 + lo) * 8;
#pragma unroll
      for (int g = 0; g < 8; ++g) {
        const uint4 v = P4[base + ((g + lo) & 7)];
        acc[4 * g + 0] = dot2f(hw, u32_as_h2(v.x), acc[4 * g + 0]);
        acc[4 * g + 1] = dot2f(hw, u32_as_h2(v.y), acc[4 * g + 1]);
        acc[4 * g + 2] = dot2f(hw, u32_as_h2(v.z), acc[4 * g + 2]);
        acc[4 * g + 3] = dot2f(hw, u32_as_h2(v.w), acc[4 * g + 3]);
      }
    }
  }

  float* orow = out + (size_t)b * 256 + j0;
#pragma unroll
  for (int q = 0; q < JT; ++q) atomicAdd(orow + q, acc[q]);
}

extern "C" void kernel_launch(void* const* d_in, const int* in_sizes, int n_in,
                              void* d_out, int out_size, void* d_ws, size_t ws_size,
                              hipStream_t stream) {
  const float* x     = (const float*)d_in[0];
  const float* coef  = (const float*)d_in[1];
  float* out = (float*)d_out;

  const size_t nB2 = (size_t)GNN * GK2;                  // f16 elements (8.4 MB)
  if (ws_size >= nB2 * 2) {
    _Float16* B2 = (_Float16*)d_ws;
    // prep_B2 also zeroes out[] (memset folded in; same-stream ordering).
    kan_prep_B2<<<(int)((size_t)GNN * 1024 / 256), 256, 0, stream>>>(
        coef, (uint32_t*)B2, (float4*)out);
    // z-major grid: linear id = x + 8*z -> XCD = i-split id; all 32 blocks
    // sharing a B2 i-window land on one XCD's L2.
    dim3 grid(KSPL2, 1, GMM / BM2);                      // (8, 1, 32) = 256 blocks
    kan_gemm9<<<grid, 512, 0, stream>>>(x, B2, out);
  } else {
    (void)hipMemsetAsync(out, 0, (size_t)out_size * sizeof(float), stream);
    dim3 grid(8192 / BT, 256 / JT, ISPL);
    kan_dot2<<<grid, 256, 0, stream>>>(x, coef, out);
  }
}

// Round 5
// 193.242 us; speedup vs baseline: 1.0292x; 1.0292x over previous
//
#include <hip/hip_runtime.h>
#include <cstdint>
#include <cstddef>

// KAN layer: out[b,j] = sum_{i,k} basis_k(tanh x[b,i]) * C[j,i,k]
// basis is 2-sparse (adjacent slots lo, lo+1); pad to 16 slots/i.
// R16: COUNTED-VMCNT granule pipeline + 2 blocks/CU.
// R13/R15 both pinned at MfmaUtil 22% with 1 block/CU, 2 waves/SIMD, and a
// vmcnt(0) drain every iter. Per m218 (counted-vs-drain0 = +38..73%) and
// m114 (co-resident overlap): BM 128 (grid 512 = 2 blocks/CU), LDS 80 KB
// (Bs ring-4 x 16 KB + As ring-2 x 8 KB), launch_bounds(512,4) for <=128
// unified regs (acc 64 AGPR). Granule = 2 i = one K=32 MFMA step; per
// granule: {rd_a(4xb128) | stage granule g+2 (2 chunks) | expand g+1 |
// s_waitcnt vmcnt(3) lgkmcnt(0) | s_barrier | sched_barrier | setprio(1)
// 16 MFMA (bf inline) setprio(0)}. vmcnt never drains to 0 in the loop;
// issue order makes vmcnt(3) uniform (prologue/steady/tail verified).
// Ring-4 + barrier convergence proves no wave-skew read/write overlap.

typedef _Float16 half2_v __attribute__((ext_vector_type(2)));
typedef __fp16  fp16x2  __attribute__((ext_vector_type(2)));
typedef _Float16 f16x8 __attribute__((ext_vector_type(8)));
typedef float f32x4 __attribute__((ext_vector_type(4)));

__device__ __forceinline__ half2_v u32_as_h2(uint32_t u) {
  union { uint32_t u; half2_v h; } c; c.u = u; return c.h;
}
__device__ __forceinline__ uint32_t h2_as_u32(half2_v h) {
  union { uint32_t u; half2_v h; } c; c.h = h; return c.u;
}
__device__ __forceinline__ half2_v cvt_pk_h2(float a, float b) {
  union { fp16x2 f; half2_v h; } c;
  c.f = __builtin_amdgcn_cvt_pkrtz(a, b);
  return c.h;
}
__device__ __forceinline__ float dot2f(half2_v a, half2_v b, float c) {
#if __has_builtin(__builtin_amdgcn_fdot2)
  return __builtin_amdgcn_fdot2(a, b, c, false);
#else
  return c + (float)a[0] * (float)b[0] + (float)a[1] * (float)b[1];
#endif
}
__device__ __forceinline__ uint16_t f16_bits(float v) {
  union { _Float16 h; uint16_t u; } c; c.h = (_Float16)v; return c.u;
}

__device__ __forceinline__ float fast_tanhf(float v) {
  const float e = __expf(2.0f * v);
  return 1.0f - 2.0f / (e + 1.0f);
}

// ---- basis-weight computation (analytic uniform knots; verified R10) ----
#define KSTEP 0.13333333333333333f
#define KINV  7.49999943750004f      // 1/(2/15 + 1e-8)
__device__ __forceinline__ void kan_weights(float xin, float& w0, float& w1, int& lo) {
  float xc = fast_tanhf(xin);
  xc = fminf(fmaxf(xc, -1.0f), 1.0f);
  int m = (int)((xc + 1.0f) * 7.5f);   // interval index; basis continuity makes +-1 ULP safe
  m = min(max(m, 0), 14);
  const float k0 = fmaf((float)m, KSTEP, -1.0f);
  const float up = (xc - k0) * KINV;
  const float dn = (k0 + KSTEP - xc) * KINV;
  // m==0: up on slot 0 | 1<=m<=11: dn on m-1, up on m | m==12: dn on 11 | m>=13: zero
  w0 = (m == 0) ? up : ((m <= 12) ? dn : 0.0f);
  w1 = (m >= 1 && m <= 11) ? up : 0.0f;
  lo = min(max(m - 1, 0), 11);
}

__device__ __forceinline__ void load_lds16(const void* g, void* l) {
  __builtin_amdgcn_global_load_lds((const __attribute__((address_space(1))) void*)g,
                                   (__attribute__((address_space(3))) void*)l, 16, 0, 0);
}

// ================= fast path =================
#define GMM 8192
#define GNN 256
#define KI  16                 // padded slots per i
#define GK2 (1024 * KI)        // 16384
#define KSPL2 8
#define IPER (1024 / KSPL2)    // 128 i per split
#define BM2 128
#define BN2 256
#define NGRAN 64               // granules per block (2 i each)
#define NBODY 16               // unrolled 4-granule bodies

// prep_B2: f16 B2[j][i*16+s], s=0..11 from coef, 12..15 zero (slot12 unused).
// Also zeroes out[] (replaces the separate memset dispatch).
__global__ __launch_bounds__(256)
void kan_prep_B2(const float* __restrict__ coef, uint32_t* __restrict__ B2,
                 float4* __restrict__ outz) {
  const int tid = blockIdx.x * 256 + threadIdx.x;   // flat (j,i), 262144
  const float* cp = coef + (size_t)tid * 13;
  uint32_t w[8];
#pragma unroll
  for (int q = 0; q < 6; ++q) w[q] = h2_as_u32(cvt_pk_h2(cp[2 * q], cp[2 * q + 1]));
  w[6] = 0u; w[7] = 0u;
  uint4* p = (uint4*)(B2 + (size_t)tid * 8);
  p[0] = make_uint4(w[0], w[1], w[2], w[3]);
  p[1] = make_uint4(w[4], w[5], w[6], w[7]);
  // out: 8192*256 f32 = 524288 float4; 262144 threads x 2
  const float4 z = make_float4(0.f, 0.f, 0.f, 0.f);
  outz[tid] = z;
  outz[tid + 262144] = z;
}

__global__ __launch_bounds__(512, 4)
void kan_gemm10(const float* __restrict__ x, const _Float16* __restrict__ B2,
                float* __restrict__ out) {
  // Bs: ring-4 granule buffers [256 j][2 i x 16 slots = 64B], chunk-swizzled
  //     (LDS chunk c' holds logical chunk c'^ (row&3)).
  // As: ring-2 granule buffers [2 i][128 rows][32B], 16B-half swap on (row>>2)&1.
  __shared__ __align__(16) char Bs[4][16384];
  __shared__ __align__(16) char As[2][8192];
  char* BsP = (char*)Bs;
  char* AsP = (char*)As;

  const int t    = threadIdx.x;
  const int lane = t & 63;
  const int wv   = t >> 6;          // 0..7
  const int wm   = (wv & 1) * 64;   // wave m-offset (of 128)
  const int wn   = (wv >> 1) * 64;  // wave n-offset (of 256)
  const int fr   = lane & 15;
  const int fq   = lane >> 4;
  const int m0   = blockIdx.z * BM2;
  const int i00  = blockIdx.x * IPER;

  // ds_read bases (all slot/frag offsets fold into 16-bit immediates)
  const int fr_swz = (((wm >> 2) + (fr >> 2)) & 1) * 16;
  const int a_base = (wm + fr) * 32 + (((fq & 1) * 16) ^ fr_swz) + (fq >> 1) * 4096;
  const int b_base = (wn + fr) * 64 + ((fq ^ (fr & 3)) * 16);

  f32x4 acc[4][4];
#pragma unroll
  for (int a = 0; a < 4; ++a)
#pragma unroll
    for (int b = 0; b < 4; ++b) acc[a][b] = (f32x4){0.f, 0.f, 0.f, 0.f};

  // B staging: granule tile 16 KB = 1024 x 16B chunks; thread t owns chunks
  // {t, 512+t}: row = n>>2, c = n&3, global chunk = c ^ (row&3).
  const int srow0 = t >> 2, sc0 = t & 3;
  const int srow1 = 128 + (t >> 2);
  const _Float16* sp0 = B2 + (size_t)srow0 * GK2 + (size_t)i00 * KI
                        + ((sc0 ^ (srow0 & 3)) * 8);
  const _Float16* sp1 = B2 + (size_t)srow1 * GK2 + (size_t)i00 * KI
                        + ((sc0 ^ (srow1 & 3)) * 8);
  // x / expand: thread owns (row = (t>>1)&127, parity = t&1, i_off = (t>>8)&1);
  // its x element for window w: x[m0+row][i00 + 4w + 2*parity + i_off].
  const int xrow   = (t >> 1) & 127;
  const int parity = t & 1;
  const int i_off  = (t >> 8) & 1;
  const float* xptr = x + (size_t)(m0 + xrow) * 1024 + i00 + 2 * parity + i_off;
  const int exp_off = (i_off * 128 + xrow) * 32;
  const int p_swz   = ((xrow >> 2) & 1) * 16;

  auto expand1 = [&](int aw, float xv) {
    float w0, w1; int lo;
    kan_weights(xv, w0, w1, lo);
    const uint32_t wp  = (uint32_t)f16_bits(w0) | ((uint32_t)f16_bits(w1) << 16);
    const uint32_t wlo = (lo & 1) ? (wp << 16) : wp;
    const uint32_t whi = (lo & 1) ? (wp >> 16) : 0u;
    const int w = lo >> 1;
    char* rb = AsP + aw + exp_off;
    *(uint4*)(rb + p_swz)        = make_uint4(0u, 0u, 0u, 0u);
    *(uint4*)(rb + (p_swz ^ 16)) = make_uint4(0u, 0u, 0u, 0u);
    *(uint32_t*)(rb + (((w + 1) * 4) ^ p_swz)) = whi;
    *(uint32_t*)(rb + ((w * 4) ^ p_swz))       = wlo;
  };

  float xa, xb, xn1, xn2;

  // ---- prologue: x(w0), x(w1); stage g0->slot0, g1->slot1; expand g0 ----
  xa = xptr[0];
  xb = xptr[4];
  load_lds16(sp0, BsP + 0 + t * 16);
  load_lds16(sp1, BsP + 0 + 8192 + t * 16);
  sp0 += 32; sp1 += 32;
  load_lds16(sp0, BsP + 16384 + t * 16);
  load_lds16(sp1, BsP + 16384 + 8192 + t * 16);
  sp0 += 32; sp1 += 32;
  if (parity == 0) expand1(0, xa);       // g0 (even) -> As[0]
  // need g0 landed; newer vmem: g1's 2 chunks -> vmcnt(2)
  asm volatile("s_waitcnt vmcnt(2) lgkmcnt(0)" ::: "memory");
  __builtin_amdgcn_s_barrier();
  __builtin_amdgcn_sched_barrier(0);

#define MFMA16(RS)                                                            \
  __builtin_amdgcn_s_setprio(1);                                              \
  _Pragma("unroll")                                                           \
  for (int ni = 0; ni < 4; ++ni) {                                            \
    const f16x8 bf = *(const f16x8*)(BsP + (RS) + b_base + ni * 1024);        \
    acc[0][ni] = __builtin_amdgcn_mfma_f32_16x16x32_f16(af0, bf, acc[0][ni], 0, 0, 0); \
    acc[1][ni] = __builtin_amdgcn_mfma_f32_16x16x32_f16(af1, bf, acc[1][ni], 0, 0, 0); \
    acc[2][ni] = __builtin_amdgcn_mfma_f32_16x16x32_f16(af2, bf, acc[2][ni], 0, 0, 0); \
    acc[3][ni] = __builtin_amdgcn_mfma_f32_16x16x32_f16(af3, bf, acc[3][ni], 0, 0, 0); \
  }                                                                           \
  __builtin_amdgcn_s_setprio(0);

// Granule body at compile-time position P (0..3) within the 4-granule body.
// Reads Bs slot P / As[P&1]; stages granule g+2 -> slot (P+2)&3; expands
// granule g+1 (parity (P+1)&1) -> As[(P+1)&1]; then counted-wait + barrier
// + 16 MFMA. ADV: pointer advance (clamped at tail so dummy stages re-read
// granule 63 in-bounds; dummy targets are dead ring slots).
#define GRAN(P, XV, ADV, XLOAD)                                               \
  {                                                                           \
    f16x8 af0 = *(const f16x8*)(AsP + ((P) & 1) * 8192 + a_base);             \
    f16x8 af1 = *(const f16x8*)(AsP + ((P) & 1) * 8192 + a_base + 512);       \
    f16x8 af2 = *(const f16x8*)(AsP + ((P) & 1) * 8192 + a_base + 1024);      \
    f16x8 af3 = *(const f16x8*)(AsP + ((P) & 1) * 8192 + a_base + 1536);      \
    load_lds16(sp0, BsP + (((P) + 2) & 3) * 16384 + t * 16);                  \
    load_lds16(sp1, BsP + (((P) + 2) & 3) * 16384 + 8192 + t * 16);           \
    sp0 += (ADV); sp1 += (ADV);                                               \
    XLOAD                                                                     \
    if (parity == (((P) + 1) & 1)) expand1((((P) + 1) & 1) * 8192, XV);       \
    asm volatile("s_waitcnt vmcnt(3) lgkmcnt(0)" ::: "memory");               \
    __builtin_amdgcn_s_barrier();                                             \
    __builtin_amdgcn_sched_barrier(0);                                        \
    MFMA16((P) * 16384)                                                       \
  }

  for (int itw = 0; itw < NBODY; ++itw) {
    const int g0 = 4 * itw;
    const int adv0 = (g0 + 3 <= NGRAN - 1) ? 32 : 0;
    const int adv1 = (g0 + 4 <= NGRAN - 1) ? 32 : 0;
    const int adv2 = (g0 + 5 <= NGRAN - 1) ? 32 : 0;
    const int adv3 = (g0 + 6 <= NGRAN - 1) ? 32 : 0;
    int xw1 = 2 * itw + 2; if (xw1 > 31) xw1 = 31;
    int xw2 = 2 * itw + 3; if (xw2 > 31) xw2 = 31;

    GRAN(0, xa, adv0, { xn1 = xptr[4 * xw1]; })
    GRAN(1, xb, adv1, { })
    GRAN(2, xb, adv2, { xn2 = xptr[4 * xw2]; })
    GRAN(3, xn1, adv3, { })

    xa = xn1; xb = xn2;
  }
#undef GRAN
#undef MFMA16

#pragma unroll
  for (int q = 0; q < 4; ++q) {
    const int gr = m0 + wm + q * 16 + fq * 4;
#pragma unroll
    for (int ni = 0; ni < 4; ++ni) {
      const int gc = wn + ni * 16 + fr;
#pragma unroll
      for (int r = 0; r < 4; ++r)
        atomicAdd(&out[(size_t)(gr + r) * GNN + gc], acc[q][ni][r]);
    }
  }
}

// ================= fallback: direct dot2 path (no workspace) =================
#define TI 8
#define BT 256
#define JT 32
#define ISPL 2
#define IRANGE (1024 / ISPL)

__global__ __launch_bounds__(256)
void kan_dot2(const float* __restrict__ x, const float* __restrict__ coef,
              float* __restrict__ out) {
  __shared__ uint32_t Plds[TI * 12 * JT];
  const int t    = threadIdx.x;
  const int b    = blockIdx.x * BT + t;
  const int j0   = blockIdx.y * JT;
  const int cbeg = blockIdx.z * (IRANGE / TI);

  float acc[JT];
#pragma unroll
  for (int q = 0; q < JT; ++q) acc[q] = 0.0f;

  const int s_jj   = t & 31;
  const int s_iloc = t >> 5;

  for (int c = cbeg; c < cbeg + IRANGE / TI; ++c) {
    const int i0 = c * TI;
    __syncthreads();
    {
      const float* cp0 = coef + ((size_t)(j0 + s_jj) * 1024 + (i0 + s_iloc)) * 13;
      float cv[13];
#pragma unroll
      for (int s = 0; s < 13; ++s) cv[s] = cp0[s];
#pragma unroll
      for (int r = 0; r < 12; ++r) {
        half2_v h; h[0] = (_Float16)cv[r]; h[1] = (_Float16)cv[r + 1];
        const int slot = ((s_jj >> 2) + r) & 7;
        Plds[(s_iloc * 12 + r) * 32 + slot * 4 + (s_jj & 3)] = h2_as_u32(h);
      }
    }
    uint32_t wr[TI]; int lor[TI];
    {
      const float* xr = x + (size_t)b * 1024 + i0;
      const float4 xa = *(const float4*)(xr);
      const float4 xb = *(const float4*)(xr + 4);
      const float xv[TI] = {xa.x, xa.y, xa.z, xa.w, xb.x, xb.y, xb.z, xb.w};
#pragma unroll
      for (int q = 0; q < TI; ++q) {
        float w0, w1; int lo;
        kan_weights(xv[q], w0, w1, lo);
        wr[q] = (uint32_t)f16_bits(w0) | ((uint32_t)f16_bits(w1) << 16);
        lor[q] = lo;
      }
    }
    __syncthreads();

    const uint4* P4 = (const uint4*)Plds;
#pragma unroll
    for (int ii = 0; ii < TI; ++ii) {
      const half2_v hw = u32_as_h2(wr[ii]);
      const int lo = lor[ii];
      const int base = (ii * 12 + lo) * 8;
#pragma unroll
      for (int g = 0; g < 8; ++g) {
        const uint4 v = P4[base + ((g + lo) & 7)];
        acc[4 * g + 0] = dot2f(hw, u32_as_h2(v.x), acc[4 * g + 0]);
        acc[4 * g + 1] = dot2f(hw, u32_as_h2(v.y), acc[4 * g + 1]);
        acc[4 * g + 2] = dot2f(hw, u32_as_h2(v.z), acc[4 * g + 2]);
        acc[4 * g + 3] = dot2f(hw, u32_as_h2(v.w), acc[4 * g + 3]);
      }
    }
  }

  float* orow = out + (size_t)b * 256 + j0;
#pragma unroll
  for (int q = 0; q < JT; ++q) atomicAdd(orow + q, acc[q]);
}

extern "C" void kernel_launch(void* const* d_in, const int* in_sizes, int n_in,
                              void* d_out, int out_size, void* d_ws, size_t ws_size,
                              hipStream_t stream) {
  const float* x     = (const float*)d_in[0];
  const float* coef  = (const float*)d_in[1];
  float* out = (float*)d_out;

  const size_t nB2 = (size_t)GNN * GK2;                  // f16 elements (8.4 MB)
  if (ws_size >= nB2 * 2) {
    _Float16* B2 = (_Float16*)d_ws;
    // prep_B2 also zeroes out[] (memset folded in; same-stream ordering).
    kan_prep_B2<<<(int)((size_t)GNN * 1024 / 256), 256, 0, stream>>>(
        coef, (uint32_t*)B2, (float4*)out);
    // z-major grid: linear id = x + 8*z -> XCD = i-split id; all 64 blocks
    // sharing a B2 i-window land on one XCD's L2. 512 blocks = 2/CU.
    dim3 grid(KSPL2, 1, GMM / BM2);                      // (8, 1, 64)
    kan_gemm10<<<grid, 512, 0, stream>>>(x, B2, out);
  } else {
    (void)hipMemsetAsync(out, 0, (size_t)out_size * sizeof(float), stream);
    dim3 grid(8192 / BT, 256 / JT, ISPL);
    kan_dot2<<<grid, 256, 0, stream>>>(x, coef, out);
  }
}